// Round 5
// baseline (11472.532 us; speedup 1.0000x reference)
//
#include <hip/hip_runtime.h>
#include <stdint.h>

#define B_   128
#define T_   64
#define V_   1024
#define TS_  64
#define H_   512
#define K_   (V_ + TS_)   // 1088

// ---------------------------------------------------------------------------
// Fused time-aware GRU scan, round 17 = r12 protocol revert + LDS x-staging.
//
// Ledger update: issue-ahead polling REFUTED twice (r13/r15: 8.7ms, r16:
// 10.2ms, FETCH +28MB). Mechanism: every extra in-flight poll round from 64
// leaders adds coherence-point traffic -> publish->visible latency inflates.
// Polling faster makes the thing polled slower. Do not revisit.
//
// r17 lever (isolated): r12's vmcnt queue pollution. In r12 ALL waves issue
// a 17-load x-row prefetch mid-step: (a) leader's first retry check drains
// the prefetch first (in-order vmcnt) -> x-row L2/HBM tail exposed in the
// poll chain ~every step; (b) __syncthreads = vmcnt(0) drain -> all waves
// stall at the barrier on their own prefetch. Fix: waves 1-3 stage the NEXT
// x row into a double-buffered LDS tile (5-6 chunks each, issued after
// their x-dots -> hides under leader's poll wait); all waves read current
// row from LDS. Leader issues ZERO non-poll global loads -> retries wait
// only on their own round. Poll/publish protocol byte-identical to r12
// (single sweep before x-dots, issue-then-check retry, sticky watchdog).
//
// Ledger: traffic knobs dead at 64 pollers (r7/r8/r9); 256 pollers
// catastrophic (r2/r11); serial-cycle cuts work (r10 +16%); heaters +2%
// (r12); issue-ahead poll refuted (r13/r15/r16).
//
// Worker structure: 64 WGs x 4 waves; wave q owns h[2q],h[2q+1]; leader
// polls the packed tagged exchange (ver<<32)|(bf16<<16)|bf16, 4 loads/lane
// over 256 words, LDS broadcast + 1 barrier; DPP wave reduction;
// wave-uniform gates; 1 tagged store per wave per step.
//
// Workspace: [0,4KB) h_buf, [4KB,+64B) done word, [4224,...) heater sink.
// LDS: hs2 2KB + x double-buffer 8KB + iv 8B ~= 10.2KB.
// ---------------------------------------------------------------------------

__device__ __forceinline__ float sigmoidf_(float x) {
    return 1.0f / (1.0f + __expf(-x));
}
__device__ __forceinline__ float tanhf_(float x) {
    x = fminf(fmaxf(x, -15.0f), 15.0f);
    const float e = __expf(2.0f * x);
    return (e - 1.0f) / (e + 1.0f);
}
__device__ __forceinline__ uint32_t bf16_rn_(float f) {
    uint32_t u = __float_as_uint(f);
    u += 0x7FFFu + ((u >> 16) & 1u);   // round-to-nearest-even
    return u >> 16;
}
__device__ __forceinline__ float bf16_to_f32_(uint32_t b) {
    return __uint_as_float(b << 16);
}

// GCN DPP full-wave sum (r10-verified): row_shr 1/2/4/8, row_bcast 15/31,
// result in lane 63, readlane-broadcast.
template <int CTRL, int RM, int BM>
__device__ __forceinline__ float dpp_add_(float a) {
    const int x = __builtin_amdgcn_update_dpp(
        0, __float_as_int(a), CTRL, RM, BM, true);
    return a + __int_as_float(x);
}
__device__ __forceinline__ float wave_sum_(float a) {
    a = dpp_add_<0x111, 0xF, 0xF>(a);
    a = dpp_add_<0x112, 0xF, 0xF>(a);
    a = dpp_add_<0x114, 0xF, 0xE>(a);
    a = dpp_add_<0x118, 0xF, 0xC>(a);
    a = dpp_add_<0x142, 0xA, 0xF>(a);
    a = dpp_add_<0x143, 0xC, 0xF>(a);
    return __int_as_float(__builtin_amdgcn_readlane(__float_as_int(a), 63));
}

__global__ __launch_bounds__(256, 1) void gru_fused(
    const float* __restrict__ visit_emb, const float* __restrict__ intervals,
    const float* __restrict__ W_time, const float* __restrict__ b_time,
    const float* __restrict__ W_ih, const float* __restrict__ W_hh,
    const float* __restrict__ b_ih, const float* __restrict__ b_hh,
    const int* __restrict__ lens,
    uint64_t* h_buf /* [2 slot][256] tagged packed */,
    float* __restrict__ out)
{
    uint32_t* done_w = (uint32_t*)((char*)h_buf + 4096);

    // =================== HEATER BLOCKS (blockIdx >= 64) ==================
    if (blockIdx.x >= 64) {
        float a0 = (float)(blockIdx.x * 256 + threadIdx.x) * 1e-6f + 1.01f;
        float a1 = a0 + 0.1f, a2 = a0 + 0.2f, a3 = a0 + 0.3f;
        const float c = 1.0000001f, d = 1e-7f;
        // bounded spin: ~512 wave-cycles/iter * 2^17 iters ~ 28ms at 2.4GHz
        for (uint32_t it = 0; it < (1u << 17); ++it) {
            #pragma unroll
            for (int i = 0; i < 64; ++i) {     // 4 indep chains -> full issue
                a0 = fmaf(a0, c, d);
                a1 = fmaf(a1, c, d);
                a2 = fmaf(a2, c, d);
                a3 = fmaf(a3, c, d);
            }
            const uint32_t f = __hip_atomic_load(done_w, __ATOMIC_RELAXED,
                                                 __HIP_MEMORY_SCOPE_AGENT);
            if (f == 1u) break;
        }
        const float s = a0 + a1 + a2 + a3;
        if (s == 1234.56789f && threadIdx.x == 0)   // defeat DCE; never true
            ((float*)((char*)h_buf + 4224))[blockIdx.x] = s;
        return;
    }

    // =================== WORKER BLOCKS ===================================
    const int lane = threadIdx.x & 63;
    const int wave = threadIdx.x >> 6;        // 0..3
    const int q    = blockIdx.x * 4 + wave;   // 0..255 global wave id
    const int j0   = q * 2;
    const int j1   = j0 + 1;

    __shared__ float2 hs2[256];               // unpacked h pairs (fp32)
    float* hs = (float*)hs2;                  // alias: hs[512]
    __shared__ float xlds[2][V_];             // double-buffered x row (8KB)
    __shared__ float ivlds[2];                // interval per buffer

    float wr0[8], wr1[8], wz0[8], wz1[8], wn0[8], wn1[8];
    #pragma unroll
    for (int u = 0; u < 8; ++u) {
        const int k = lane + 64 * u;
        wr0[u] = W_hh[(size_t)j0 * H_ + k];
        wr1[u] = W_hh[(size_t)j1 * H_ + k];
        wz0[u] = W_hh[(size_t)(H_ + j0) * H_ + k];
        wz1[u] = W_hh[(size_t)(H_ + j1) * H_ + k];
        wn0[u] = W_hh[(size_t)(2 * H_ + j0) * H_ + k];
        wn1[u] = W_hh[(size_t)(2 * H_ + j1) * H_ + k];
    }
    float ir0[17], ir1[17], iz0[17], iz1[17], in0[17], in1[17];
    #pragma unroll
    for (int u = 0; u < 16; ++u) {
        const int k = lane + 64 * u;
        ir0[u] = W_ih[(size_t)j0 * K_ + k];
        ir1[u] = W_ih[(size_t)j1 * K_ + k];
        iz0[u] = W_ih[(size_t)(H_ + j0) * K_ + k];
        iz1[u] = W_ih[(size_t)(H_ + j1) * K_ + k];
        in0[u] = W_ih[(size_t)(2 * H_ + j0) * K_ + k];
        in1[u] = W_ih[(size_t)(2 * H_ + j1) * K_ + k];
    }
    ir0[16] = W_ih[(size_t)j0 * K_ + V_ + lane];
    ir1[16] = W_ih[(size_t)j1 * K_ + V_ + lane];
    iz0[16] = W_ih[(size_t)(H_ + j0) * K_ + V_ + lane];
    iz1[16] = W_ih[(size_t)(H_ + j1) * K_ + V_ + lane];
    in0[16] = W_ih[(size_t)(2 * H_ + j0) * K_ + V_ + lane];
    in1[16] = W_ih[(size_t)(2 * H_ + j1) * K_ + V_ + lane];

    const float wt = W_time[lane];
    const float bt = b_time[lane];

    const float bir0 = b_ih[j0],          bir1 = b_ih[j1];
    const float biz0 = b_ih[H_ + j0],     biz1 = b_ih[H_ + j1];
    const float bin0 = b_ih[2 * H_ + j0], bin1 = b_ih[2 * H_ + j1];
    const float bhr0 = b_hh[j0],          bhr1 = b_hh[j1];
    const float bhz0 = b_hh[H_ + j0],     bhz1 = b_hh[H_ + j1];
    const float bhn0 = b_hh[2 * H_ + j0], bhn1 = b_hh[2 * H_ + j1];

    float hj0 = 0.0f, hj1 = 0.0f;             // wave-uniform state
    uint32_t ver  = 1;    // ver 1 == initial zero state, lives in slot 1
    uint32_t dead = 0;    // leader watchdog state (wave-uniform)

    if (lane == 0)
        __hip_atomic_store(&h_buf[(ver & 1) * 256 + q], (uint64_t)ver << 32,
                           __ATOMIC_RELAXED, __HIP_MEMORY_SCOPE_AGENT);

    // ---- pre-stage the first non-empty sample's row 0 into xlds[1] ------
    // (first executed step has entry ver==1 and reads xlds[ver&1]==xlds[1])
    {
        int b0 = -1;
        for (int j = 0; j < B_; ++j) { if (lens[j] > 0) { b0 = j; break; } }
        if (b0 >= 0 && wave != 0) {
            const float* vrow = visit_emb + (size_t)(b0 * T_) * V_;
            for (int c = wave - 1; c < 16; c += 3)
                xlds[1][lane + 64 * c] = vrow[lane + 64 * c];
            if (wave == 1 && lane == 0) ivlds[1] = intervals[b0 * T_];
        }
    }
    __syncthreads();

    for (int b = 0; b < B_; ++b) {
        const int L = lens[b];
        // next non-empty sample (for cross-sample staging at t == L-1)
        int nb = -1;
        if (L > 0) {
            for (int j = b + 1; j < B_; ++j)
                { if (lens[j] > 0) { nb = j; break; } }
        }
        for (int t = 0; t < L; ++t) {
            const uint64_t* src = h_buf + (ver & 1) * 256;
            const int p = ver & 1;            // current x buffer
            uint64_t w[4];

            // ---- leader: ISSUE first sweep before x-dots ----------------
            if (wave == 0) {
                #pragma unroll
                for (int u = 0; u < 4; ++u)
                    w[u] = __hip_atomic_load(&src[lane + 64 * u],
                                             __ATOMIC_RELAXED,
                                             __HIP_MEMORY_SCOPE_AGENT);
            }

            // ---- x from LDS + x-side dots (overlap the sweep) -----------
            float xv[16];
            #pragma unroll
            for (int u = 0; u < 16; ++u) xv[u] = xlds[p][lane + 64 * u];
            const float iv = ivlds[p];

            const float xt = fmaf(iv, wt, bt);
            float ar0 = ir0[16] * xt, ar1 = ir1[16] * xt;
            float az0 = iz0[16] * xt, az1 = iz1[16] * xt;
            float xn0 = in0[16] * xt, xn1 = in1[16] * xt;
            #pragma unroll
            for (int u = 0; u < 16; ++u) {
                ar0 = fmaf(ir0[u], xv[u], ar0);
                ar1 = fmaf(ir1[u], xv[u], ar1);
                az0 = fmaf(iz0[u], xv[u], az0);
                az1 = fmaf(iz1[u], xv[u], az1);
                xn0 = fmaf(in0[u], xv[u], xn0);
                xn1 = fmaf(in1[u], xv[u], xn1);
            }

            // ---- waves 1..3: stage NEXT row into xlds[p^1] --------------
            // (issued after their x-dots; global-load latency hides under
            //  the leader's poll wait; ds_writes drain at the barrier)
            if (wave != 0) {
                int sb = -1, st = 0;
                if (t + 1 < L)      { sb = b;  st = t + 1; }
                else if (nb >= 0)   { sb = nb; st = 0;     }
                if (sb >= 0) {
                    const float* vrow =
                        visit_emb + (size_t)(sb * T_ + st) * V_;
                    for (int c = wave - 1; c < 16; c += 3)
                        xlds[p ^ 1][lane + 64 * c] = vrow[lane + 64 * c];
                    if (wave == 1 && lane == 0)
                        ivlds[p ^ 1] = intervals[sb * T_ + st];
                }
            }

            // ---- leader: check tags, retry (queue = polls ONLY), LDS ----
            if (wave == 0) {
                if (!dead) {
                    bool ok = true;
                    #pragma unroll
                    for (int u = 0; u < 4; ++u)
                        ok = ok && ((uint32_t)(w[u] >> 32) == ver);
                    uint32_t tries = 0;
                    while (!__all(ok)) {
                        if (++tries > (1u << 17)) { dead = 1; break; }
                        ok = true;
                        #pragma unroll
                        for (int u = 0; u < 4; ++u) {
                            w[u] = __hip_atomic_load(&src[lane + 64 * u],
                                                     __ATOMIC_RELAXED,
                                                     __HIP_MEMORY_SCOPE_AGENT);
                            ok = ok && ((uint32_t)(w[u] >> 32) == ver);
                        }
                    }
                }
                #pragma unroll
                for (int u = 0; u < 4; ++u) {
                    const uint32_t d = (uint32_t)w[u];
                    hs2[lane + 64 * u] =
                        make_float2(bf16_to_f32_(d & 0xFFFFu),
                                    bf16_to_f32_(d >> 16));
                }
            }
            __syncthreads();

            float h[8];
            #pragma unroll
            for (int u = 0; u < 8; ++u) h[u] = hs[lane + 64 * u];

            // ---- h-side dots; r/z merged with x-side, n kept split ------
            float hn0 = 0.0f, hn1 = 0.0f;
            #pragma unroll
            for (int u = 0; u < 8; ++u) {
                ar0 = fmaf(wr0[u], h[u], ar0);
                ar1 = fmaf(wr1[u], h[u], ar1);
                az0 = fmaf(wz0[u], h[u], az0);
                az1 = fmaf(wz1[u], h[u], az1);
                hn0 = fmaf(wn0[u], h[u], hn0);
                hn1 = fmaf(wn1[u], h[u], hn1);
            }

            // ---- 8 pipelined DPP wave sums (VALU, no LDS rounds) --------
            const float sr0 = wave_sum_(ar0), sr1 = wave_sum_(ar1);
            const float sz0 = wave_sum_(az0), sz1 = wave_sum_(az1);
            const float sx0 = wave_sum_(xn0), sx1 = wave_sum_(xn1);
            const float sh0 = wave_sum_(hn0), sh1 = wave_sum_(hn1);

            // ---- gates & recurrence (wave-uniform) ----------------------
            const float r0 = sigmoidf_(sr0 + bir0 + bhr0);
            const float r1 = sigmoidf_(sr1 + bir1 + bhr1);
            const float z0 = sigmoidf_(sz0 + biz0 + bhz0);
            const float z1 = sigmoidf_(sz1 + biz1 + bhz1);
            const float n0 = tanhf_(sx0 + bin0 + r0 * (sh0 + bhn0));
            const float n1 = tanhf_(sx1 + bin1 + r1 * (sh1 + bhn1));
            hj0 = (1.0f - z0) * n0 + z0 * hj0;
            hj1 = (1.0f - z1) * n1 + z1 * hj1;

            // ---- publish ONE tagged packed word per wave ----------------
            ++ver;
            if (lane == 0) {
                const uint32_t packed =
                    bf16_rn_(hj0) | (bf16_rn_(hj1) << 16);
                __hip_atomic_store(&h_buf[(ver & 1) * 256 + q],
                    ((uint64_t)ver << 32) | (uint64_t)packed,
                    __ATOMIC_RELAXED, __HIP_MEMORY_SCOPE_AGENT);
            }
        }
        // out[b] = h after sample b's (possibly empty) segment
        if (lane < 2) out[b * H_ + j0 + lane] = (lane == 0) ? hj0 : hj1;
    }

    // last wave signals the heaters to stop (everyone else is within +-1
    // step of q==255, so heat never extends the dispatch)
    if (q == 255 && lane == 0)
        __hip_atomic_store(done_w, 1u, __ATOMIC_RELAXED,
                           __HIP_MEMORY_SCOPE_AGENT);
}

// ---------------------------------------------------------------------------
extern "C" void kernel_launch(void* const* d_in, const int* in_sizes, int n_in,
                              void* d_out, int out_size, void* d_ws, size_t ws_size,
                              hipStream_t stream)
{
    const float* visit_emb = (const float*)d_in[0];
    const float* intervals = (const float*)d_in[1];
    const float* W_time    = (const float*)d_in[2];
    const float* b_time    = (const float*)d_in[3];
    const float* W_ih      = (const float*)d_in[4];
    const float* W_hh      = (const float*)d_in[5];
    const float* b_ih      = (const float*)d_in[6];
    const float* b_hh      = (const float*)d_in[7];
    const int*   lens      = (const int*)d_in[8];
    float*       out       = (float*)d_out;

    // workspace: [0,4KB) packed tagged h exchange; [4KB) done; [4224) sink
    uint64_t* h_buf = (uint64_t*)d_ws;

    gru_fused<<<256, 256, 0, stream>>>(visit_emb, intervals, W_time, b_time,
                                       W_ih, W_hh, b_ih, b_hh, lens, h_buf, out);
}

// Round 7
// 7275.360 us; speedup vs baseline: 1.5769x; 1.5769x over previous
//
#include <hip/hip_runtime.h>
#include <stdint.h>

#define B_   128
#define T_   64
#define V_   1024
#define TS_  64
#define H_   512
#define K_   (V_ + TS_)   // 1088

// ---------------------------------------------------------------------------
// Fused time-aware GRU scan, round 19 = r18 RESUBMIT (infra failure, no data;
// same "container failed twice" + empty-timing signature as r13/r14 which
// r15 then ran fine). Kernel is bounded-termination: heater cap 2^15 iters
// (~28ms), sticky 2^21-try worker watchdog. Content: r12 VERBATIM worker
// protocol (7.26ms anchor) + heater poll rate cut 4x (1024 FMAs between
// done_w checks).
//
// Ledger (do-not-revisit list):
//   - issue-ahead/pipelined polling REFUTED (r13/r15: 8.7ms, r16: 10.2ms;
//     FETCH +28MB). More in-flight poll rounds from 64 leaders inflate
//     publish->visible latency at the coherence point.
//   - LDS x-staging REFUTED (r17: 11.5ms). ds_write needs vmcnt drain on its
//     global-load source + barrier drains lgkmcnt -> x-row load latency
//     lands INSIDE the step's barrier window. r12's register prefetch has a
//     full step (~1.8us) of slack instead.
//   - traffic knobs dead at 64 pollers (r7 -7%, r8 -89%, r9 +4%);
//     256 pollers catastrophic (r2 11.2ms, r11 16.4ms).
//   - serial-cycle cuts work (r10 +16%); heaters +2% (r12).
// Model: per-step ~380cy post-h-arrival issue work + ~3000-3900cy comm RT
// (publish visibility + poll resolve). Comm RT dominates; every reshaping
// attempt lost. This round only REDUCES background coherence traffic:
// 768 heater waves polled done_w every ~256 FMAs ~ 1.5 loads/cy at the
// same fabric that services h_buf -- cut 4x.
//
// Worker structure (r10, byte-identical to the 7.26ms round-0 kernel):
// 64 WGs x 4 waves; wave q owns h[2q],h[2q+1]; leader wave polls the packed
// tagged exchange (ver<<32)|(bf16(hj1)<<16)|bf16(hj0), 4 loads/lane over
// 256 words, issued BEFORE the x-dots (overlap), LDS broadcast + 1 barrier;
// DPP wave reduction; wave-uniform gates; 1 tagged store per wave per step.
//
// Workspace: [0,4KB) h_buf, [4KB,+64B) done word, [4224,...) heater sink.
// ---------------------------------------------------------------------------

__device__ __forceinline__ float sigmoidf_(float x) {
    return 1.0f / (1.0f + __expf(-x));
}
__device__ __forceinline__ float tanhf_(float x) {
    x = fminf(fmaxf(x, -15.0f), 15.0f);
    const float e = __expf(2.0f * x);
    return (e - 1.0f) / (e + 1.0f);
}
__device__ __forceinline__ uint32_t bf16_rn_(float f) {
    uint32_t u = __float_as_uint(f);
    u += 0x7FFFu + ((u >> 16) & 1u);   // round-to-nearest-even
    return u >> 16;
}
__device__ __forceinline__ float bf16_to_f32_(uint32_t b) {
    return __uint_as_float(b << 16);
}

// GCN DPP full-wave sum (r10-verified): row_shr 1/2/4/8, row_bcast 15/31,
// result in lane 63, readlane-broadcast.
template <int CTRL, int RM, int BM>
__device__ __forceinline__ float dpp_add_(float a) {
    const int x = __builtin_amdgcn_update_dpp(
        0, __float_as_int(a), CTRL, RM, BM, true);
    return a + __int_as_float(x);
}
__device__ __forceinline__ float wave_sum_(float a) {
    a = dpp_add_<0x111, 0xF, 0xF>(a);
    a = dpp_add_<0x112, 0xF, 0xF>(a);
    a = dpp_add_<0x114, 0xF, 0xE>(a);
    a = dpp_add_<0x118, 0xF, 0xC>(a);
    a = dpp_add_<0x142, 0xA, 0xF>(a);
    a = dpp_add_<0x143, 0xC, 0xF>(a);
    return __int_as_float(__builtin_amdgcn_readlane(__float_as_int(a), 63));
}

__global__ __launch_bounds__(256, 1) void gru_fused(
    const float* __restrict__ visit_emb, const float* __restrict__ intervals,
    const float* __restrict__ W_time, const float* __restrict__ b_time,
    const float* __restrict__ W_ih, const float* __restrict__ W_hh,
    const float* __restrict__ b_ih, const float* __restrict__ b_hh,
    const int* __restrict__ lens,
    uint64_t* h_buf /* [2 slot][256] tagged packed */,
    float* __restrict__ out)
{
    uint32_t* done_w = (uint32_t*)((char*)h_buf + 4096);

    // =================== HEATER BLOCKS (blockIdx >= 64) ==================
    if (blockIdx.x >= 64) {
        float a0 = (float)(blockIdx.x * 256 + threadIdx.x) * 1e-6f + 1.01f;
        float a1 = a0 + 0.1f, a2 = a0 + 0.2f, a3 = a0 + 0.3f;
        const float c = 1.0000001f, d = 1e-7f;
        // poll done_w every ~1024 FMAs (4x less coherence traffic than r12);
        // bounded spin: ~2048 wave-cycles/iter * 2^15 iters ~ 28ms at 2.4GHz
        for (uint32_t it = 0; it < (1u << 15); ++it) {
            #pragma unroll
            for (int o = 0; o < 4; ++o) {
                #pragma unroll
                for (int i = 0; i < 64; ++i) { // 4 indep chains -> full issue
                    a0 = fmaf(a0, c, d);
                    a1 = fmaf(a1, c, d);
                    a2 = fmaf(a2, c, d);
                    a3 = fmaf(a3, c, d);
                }
            }
            const uint32_t f = __hip_atomic_load(done_w, __ATOMIC_RELAXED,
                                                 __HIP_MEMORY_SCOPE_AGENT);
            if (f == 1u) break;
        }
        const float s = a0 + a1 + a2 + a3;
        if (s == 1234.56789f && threadIdx.x == 0)   // defeat DCE; never true
            ((float*)((char*)h_buf + 4224))[blockIdx.x] = s;
        return;
    }

    // =================== WORKER BLOCKS (r12 verbatim) ====================
    const int lane = threadIdx.x & 63;
    const int wave = threadIdx.x >> 6;        // 0..3
    const int q    = blockIdx.x * 4 + wave;   // 0..255 global wave id
    const int j0   = q * 2;
    const int j1   = j0 + 1;

    __shared__ float2 hs2[256];               // unpacked h pairs (fp32)
    float* hs = (float*)hs2;                  // alias: hs[512]

    float wr0[8], wr1[8], wz0[8], wz1[8], wn0[8], wn1[8];
    #pragma unroll
    for (int u = 0; u < 8; ++u) {
        const int k = lane + 64 * u;
        wr0[u] = W_hh[(size_t)j0 * H_ + k];
        wr1[u] = W_hh[(size_t)j1 * H_ + k];
        wz0[u] = W_hh[(size_t)(H_ + j0) * H_ + k];
        wz1[u] = W_hh[(size_t)(H_ + j1) * H_ + k];
        wn0[u] = W_hh[(size_t)(2 * H_ + j0) * H_ + k];
        wn1[u] = W_hh[(size_t)(2 * H_ + j1) * H_ + k];
    }
    float ir0[17], ir1[17], iz0[17], iz1[17], in0[17], in1[17];
    #pragma unroll
    for (int u = 0; u < 16; ++u) {
        const int k = lane + 64 * u;
        ir0[u] = W_ih[(size_t)j0 * K_ + k];
        ir1[u] = W_ih[(size_t)j1 * K_ + k];
        iz0[u] = W_ih[(size_t)(H_ + j0) * K_ + k];
        iz1[u] = W_ih[(size_t)(H_ + j1) * K_ + k];
        in0[u] = W_ih[(size_t)(2 * H_ + j0) * K_ + k];
        in1[u] = W_ih[(size_t)(2 * H_ + j1) * K_ + k];
    }
    ir0[16] = W_ih[(size_t)j0 * K_ + V_ + lane];
    ir1[16] = W_ih[(size_t)j1 * K_ + V_ + lane];
    iz0[16] = W_ih[(size_t)(H_ + j0) * K_ + V_ + lane];
    iz1[16] = W_ih[(size_t)(H_ + j1) * K_ + V_ + lane];
    in0[16] = W_ih[(size_t)(2 * H_ + j0) * K_ + V_ + lane];
    in1[16] = W_ih[(size_t)(2 * H_ + j1) * K_ + V_ + lane];

    const float wt = W_time[lane];
    const float bt = b_time[lane];

    const float bir0 = b_ih[j0],          bir1 = b_ih[j1];
    const float biz0 = b_ih[H_ + j0],     biz1 = b_ih[H_ + j1];
    const float bin0 = b_ih[2 * H_ + j0], bin1 = b_ih[2 * H_ + j1];
    const float bhr0 = b_hh[j0],          bhr1 = b_hh[j1];
    const float bhz0 = b_hh[H_ + j0],     bhz1 = b_hh[H_ + j1];
    const float bhn0 = b_hh[2 * H_ + j0], bhn1 = b_hh[2 * H_ + j1];

    float hj0 = 0.0f, hj1 = 0.0f;             // wave-uniform state
    uint32_t ver  = 1;    // ver 1 == initial zero state, lives in slot 1
    uint32_t dead = 0;    // leader watchdog state (wave-uniform)

    if (lane == 0)
        __hip_atomic_store(&h_buf[(ver & 1) * 256 + q], (uint64_t)ver << 32,
                           __ATOMIC_RELAXED, __HIP_MEMORY_SCOPE_AGENT);

    float xv[16];
    float iv = 0.0f;

    for (int b = 0; b < B_; ++b) {
        const int L = lens[b];
        if (L > 0) {
            iv = intervals[b * T_];
            const float* vrow = visit_emb + (size_t)(b * T_) * V_;
            #pragma unroll
            for (int u = 0; u < 16; ++u) xv[u] = vrow[lane + 64 * u];
        }
        for (int t = 0; t < L; ++t) {
            // ---- leader: ISSUE first sweep before x-dots ----------------
            const uint64_t* src = h_buf + (ver & 1) * 256;
            uint64_t w[4];
            if (wave == 0) {
                #pragma unroll
                for (int u = 0; u < 4; ++u)
                    w[u] = __hip_atomic_load(&src[lane + 64 * u],
                                             __ATOMIC_RELAXED,
                                             __HIP_MEMORY_SCOPE_AGENT);
            }

            // ---- x-side dots (h-independent; overlap the sweep) ---------
            const float xt = fmaf(iv, wt, bt);
            float ar0 = ir0[16] * xt, ar1 = ir1[16] * xt;
            float az0 = iz0[16] * xt, az1 = iz1[16] * xt;
            float xn0 = in0[16] * xt, xn1 = in1[16] * xt;
            #pragma unroll
            for (int u = 0; u < 16; ++u) {
                ar0 = fmaf(ir0[u], xv[u], ar0);
                ar1 = fmaf(ir1[u], xv[u], ar1);
                az0 = fmaf(iz0[u], xv[u], az0);
                az1 = fmaf(iz1[u], xv[u], az1);
                xn0 = fmaf(in0[u], xv[u], xn0);
                xn1 = fmaf(in1[u], xv[u], xn1);
            }
            // ---- prefetch next step's x row (in flight across barrier) --
            if (t + 1 < L) {
                iv = intervals[b * T_ + t + 1];
                const float* vrow = visit_emb + (size_t)(b * T_ + t + 1) * V_;
                #pragma unroll
                for (int u = 0; u < 16; ++u) xv[u] = vrow[lane + 64 * u];
            }

            // ---- leader: check tags (waitcnt lands here), retry, LDS ----
            if (wave == 0) {
                if (!dead) {
                    bool ok = true;
                    #pragma unroll
                    for (int u = 0; u < 4; ++u)
                        ok = ok && ((uint32_t)(w[u] >> 32) == ver);
                    uint32_t tries = 0;
                    while (!__all(ok)) {
                        if (++tries > (1u << 21)) { dead = 1; break; }
                        ok = true;
                        #pragma unroll
                        for (int u = 0; u < 4; ++u) {
                            w[u] = __hip_atomic_load(&src[lane + 64 * u],
                                                     __ATOMIC_RELAXED,
                                                     __HIP_MEMORY_SCOPE_AGENT);
                            ok = ok && ((uint32_t)(w[u] >> 32) == ver);
                        }
                    }
                }
                #pragma unroll
                for (int u = 0; u < 4; ++u) {
                    const uint32_t d = (uint32_t)w[u];
                    hs2[lane + 64 * u] =
                        make_float2(bf16_to_f32_(d & 0xFFFFu),
                                    bf16_to_f32_(d >> 16));
                }
            }
            __syncthreads();

            float h[8];
            #pragma unroll
            for (int u = 0; u < 8; ++u) h[u] = hs[lane + 64 * u];

            // ---- h-side dots; r/z merged with x-side, n kept split ------
            float hn0 = 0.0f, hn1 = 0.0f;
            #pragma unroll
            for (int u = 0; u < 8; ++u) {
                ar0 = fmaf(wr0[u], h[u], ar0);
                ar1 = fmaf(wr1[u], h[u], ar1);
                az0 = fmaf(wz0[u], h[u], az0);
                az1 = fmaf(wz1[u], h[u], az1);
                hn0 = fmaf(wn0[u], h[u], hn0);
                hn1 = fmaf(wn1[u], h[u], hn1);
            }

            // ---- 8 pipelined DPP wave sums (VALU, no LDS rounds) --------
            const float sr0 = wave_sum_(ar0), sr1 = wave_sum_(ar1);
            const float sz0 = wave_sum_(az0), sz1 = wave_sum_(az1);
            const float sx0 = wave_sum_(xn0), sx1 = wave_sum_(xn1);
            const float sh0 = wave_sum_(hn0), sh1 = wave_sum_(hn1);

            // ---- gates & recurrence (wave-uniform) ----------------------
            const float r0 = sigmoidf_(sr0 + bir0 + bhr0);
            const float r1 = sigmoidf_(sr1 + bir1 + bhr1);
            const float z0 = sigmoidf_(sz0 + biz0 + bhz0);
            const float z1 = sigmoidf_(sz1 + biz1 + bhz1);
            const float n0 = tanhf_(sx0 + bin0 + r0 * (sh0 + bhn0));
            const float n1 = tanhf_(sx1 + bin1 + r1 * (sh1 + bhn1));
            hj0 = (1.0f - z0) * n0 + z0 * hj0;
            hj1 = (1.0f - z1) * n1 + z1 * hj1;

            // ---- publish ONE tagged packed word per wave ----------------
            ++ver;
            if (lane == 0) {
                const uint32_t packed =
                    bf16_rn_(hj0) | (bf16_rn_(hj1) << 16);
                __hip_atomic_store(&h_buf[(ver & 1) * 256 + q],
                    ((uint64_t)ver << 32) | (uint64_t)packed,
                    __ATOMIC_RELAXED, __HIP_MEMORY_SCOPE_AGENT);
            }
        }
        // out[b] = h after sample b's (possibly empty) segment
        if (lane < 2) out[b * H_ + j0 + lane] = (lane == 0) ? hj0 : hj1;
    }

    // last wave signals the heaters to stop (everyone else is within +-1
    // step of q==255, so heat never extends the dispatch)
    if (q == 255 && lane == 0)
        __hip_atomic_store(done_w, 1u, __ATOMIC_RELAXED,
                           __HIP_MEMORY_SCOPE_AGENT);
}

// ---------------------------------------------------------------------------
extern "C" void kernel_launch(void* const* d_in, const int* in_sizes, int n_in,
                              void* d_out, int out_size, void* d_ws, size_t ws_size,
                              hipStream_t stream)
{
    const float* visit_emb = (const float*)d_in[0];
    const float* intervals = (const float*)d_in[1];
    const float* W_time    = (const float*)d_in[2];
    const float* b_time    = (const float*)d_in[3];
    const float* W_ih      = (const float*)d_in[4];
    const float* W_hh      = (const float*)d_in[5];
    const float* b_ih      = (const float*)d_in[6];
    const float* b_hh      = (const float*)d_in[7];
    const int*   lens      = (const int*)d_in[8];
    float*       out       = (float*)d_out;

    // workspace: [0,4KB) packed tagged h exchange; [4KB) done; [4224) sink
    uint64_t* h_buf = (uint64_t*)d_ws;

    gru_fused<<<256, 256, 0, stream>>>(visit_emb, intervals, W_time, b_time,
                                       W_ih, W_hh, b_ih, b_hh, lens, h_buf, out);
}

// Round 8
// 6939.085 us; speedup vs baseline: 1.6533x; 1.0485x over previous
//
#include <hip/hip_runtime.h>
#include <stdint.h>

#define B_   128
#define T_   64
#define V_   1024
#define TS_  64
#define H_   512
#define K_   (V_ + TS_)   // 1088

// ---------------------------------------------------------------------------
// Fused time-aware GRU scan, round 20 = r18 (anchor-parity, 7.28ms) + lane-63
// publish path (serial-cut family -- the only family that has ever won).
//
// Change: wave_sum no longer readlane-broadcasts. Lane 63 holds all 8 DPP
// sums natively; gates are computed SIMT-wide (only lane 63 meaningful);
// h state (hj0/hj1) is lane-63-resident; the tagged publish store issues
// from lane 63 directly. Removes 8 v_readlane VALU->SALU round trips
// (~50-120cy) from the per-step publish critical path. out[] written from
// lane 63 at sample boundaries (128x, off hot path). Zero traffic change.
//
// Ledger (do-not-revisit):
//   - issue-ahead/pipelined polling REFUTED (r13/r15 8.7ms, r16 10.2ms).
//   - LDS x-staging REFUTED (r17 11.5ms): ds_write vmcnt drain + barrier
//     lgkmcnt drain put the x-row load INSIDE the step's barrier window.
//   - heater poll-rate 4x cut NEUTRAL (r19 7.28 = anchor): background
//     coherence traffic is not the limiter.
//   - traffic knobs dead at 64 pollers (r7/r8/r9); 256 pollers catastrophic.
//   - serial-cycle cuts WORK (r10 +16%).
// Model: step ~1.8us = cross-XCD publish visibility (~600-900cy) + poll
// resolve quantization (~700cy) + straggler max-of-256 + ~500cy compute
// tail. This round shaves the compute tail.
//
// Worker structure: 64 WGs x 4 waves; wave q owns h[2q],h[2q+1]; leader
// polls the packed tagged exchange (ver<<32)|(bf16(hj1)<<16)|bf16(hj0),
// 4 loads/lane over 256 words, issued BEFORE x-dots, LDS broadcast +
// 1 barrier; DPP wave reduction; 1 tagged store per wave per step.
// Workspace: [0,4KB) h_buf, [4KB,+64B) done word, [4224,...) heater sink.
// ---------------------------------------------------------------------------

__device__ __forceinline__ float sigmoidf_(float x) {
    return 1.0f / (1.0f + __expf(-x));
}
__device__ __forceinline__ float tanhf_(float x) {
    x = fminf(fmaxf(x, -15.0f), 15.0f);
    const float e = __expf(2.0f * x);
    return (e - 1.0f) / (e + 1.0f);
}
__device__ __forceinline__ uint32_t bf16_rn_(float f) {
    uint32_t u = __float_as_uint(f);
    u += 0x7FFFu + ((u >> 16) & 1u);   // round-to-nearest-even
    return u >> 16;
}
__device__ __forceinline__ float bf16_to_f32_(uint32_t b) {
    return __uint_as_float(b << 16);
}

// GCN DPP partial-wave sum: after this chain the FULL 64-lane sum is valid
// in lane 63 (same chain as the r10-verified wave_sum_, minus the final
// readlane broadcast).
template <int CTRL, int RM, int BM>
__device__ __forceinline__ float dpp_add_(float a) {
    const int x = __builtin_amdgcn_update_dpp(
        0, __float_as_int(a), CTRL, RM, BM, true);
    return a + __int_as_float(x);
}
__device__ __forceinline__ float wave_sum63_(float a) {
    a = dpp_add_<0x111, 0xF, 0xF>(a);
    a = dpp_add_<0x112, 0xF, 0xF>(a);
    a = dpp_add_<0x114, 0xF, 0xE>(a);
    a = dpp_add_<0x118, 0xF, 0xC>(a);
    a = dpp_add_<0x142, 0xA, 0xF>(a);
    a = dpp_add_<0x143, 0xC, 0xF>(a);
    return a;                          // valid in lane 63 only
}

__global__ __launch_bounds__(256, 1) void gru_fused(
    const float* __restrict__ visit_emb, const float* __restrict__ intervals,
    const float* __restrict__ W_time, const float* __restrict__ b_time,
    const float* __restrict__ W_ih, const float* __restrict__ W_hh,
    const float* __restrict__ b_ih, const float* __restrict__ b_hh,
    const int* __restrict__ lens,
    uint64_t* h_buf /* [2 slot][256] tagged packed */,
    float* __restrict__ out)
{
    uint32_t* done_w = (uint32_t*)((char*)h_buf + 4096);

    // =================== HEATER BLOCKS (blockIdx >= 64) ==================
    if (blockIdx.x >= 64) {
        float a0 = (float)(blockIdx.x * 256 + threadIdx.x) * 1e-6f + 1.01f;
        float a1 = a0 + 0.1f, a2 = a0 + 0.2f, a3 = a0 + 0.3f;
        const float c = 1.0000001f, d = 1e-7f;
        // poll done_w every ~1024 FMAs; bounded spin ~28ms at 2.4GHz
        for (uint32_t it = 0; it < (1u << 15); ++it) {
            #pragma unroll
            for (int o = 0; o < 4; ++o) {
                #pragma unroll
                for (int i = 0; i < 64; ++i) { // 4 indep chains -> full issue
                    a0 = fmaf(a0, c, d);
                    a1 = fmaf(a1, c, d);
                    a2 = fmaf(a2, c, d);
                    a3 = fmaf(a3, c, d);
                }
            }
            const uint32_t f = __hip_atomic_load(done_w, __ATOMIC_RELAXED,
                                                 __HIP_MEMORY_SCOPE_AGENT);
            if (f == 1u) break;
        }
        const float s = a0 + a1 + a2 + a3;
        if (s == 1234.56789f && threadIdx.x == 0)   // defeat DCE; never true
            ((float*)((char*)h_buf + 4224))[blockIdx.x] = s;
        return;
    }

    // =================== WORKER BLOCKS ===================================
    const int lane = threadIdx.x & 63;
    const int wave = threadIdx.x >> 6;        // 0..3
    const int q    = blockIdx.x * 4 + wave;   // 0..255 global wave id
    const int j0   = q * 2;
    const int j1   = j0 + 1;

    __shared__ float2 hs2[256];               // unpacked h pairs (fp32)
    float* hs = (float*)hs2;                  // alias: hs[512]

    float wr0[8], wr1[8], wz0[8], wz1[8], wn0[8], wn1[8];
    #pragma unroll
    for (int u = 0; u < 8; ++u) {
        const int k = lane + 64 * u;
        wr0[u] = W_hh[(size_t)j0 * H_ + k];
        wr1[u] = W_hh[(size_t)j1 * H_ + k];
        wz0[u] = W_hh[(size_t)(H_ + j0) * H_ + k];
        wz1[u] = W_hh[(size_t)(H_ + j1) * H_ + k];
        wn0[u] = W_hh[(size_t)(2 * H_ + j0) * H_ + k];
        wn1[u] = W_hh[(size_t)(2 * H_ + j1) * H_ + k];
    }
    float ir0[17], ir1[17], iz0[17], iz1[17], in0[17], in1[17];
    #pragma unroll
    for (int u = 0; u < 16; ++u) {
        const int k = lane + 64 * u;
        ir0[u] = W_ih[(size_t)j0 * K_ + k];
        ir1[u] = W_ih[(size_t)j1 * K_ + k];
        iz0[u] = W_ih[(size_t)(H_ + j0) * K_ + k];
        iz1[u] = W_ih[(size_t)(H_ + j1) * K_ + k];
        in0[u] = W_ih[(size_t)(2 * H_ + j0) * K_ + k];
        in1[u] = W_ih[(size_t)(2 * H_ + j1) * K_ + k];
    }
    ir0[16] = W_ih[(size_t)j0 * K_ + V_ + lane];
    ir1[16] = W_ih[(size_t)j1 * K_ + V_ + lane];
    iz0[16] = W_ih[(size_t)(H_ + j0) * K_ + V_ + lane];
    iz1[16] = W_ih[(size_t)(H_ + j1) * K_ + V_ + lane];
    in0[16] = W_ih[(size_t)(2 * H_ + j0) * K_ + V_ + lane];
    in1[16] = W_ih[(size_t)(2 * H_ + j1) * K_ + V_ + lane];

    const float wt = W_time[lane];
    const float bt = b_time[lane];

    const float bir0 = b_ih[j0],          bir1 = b_ih[j1];
    const float biz0 = b_ih[H_ + j0],     biz1 = b_ih[H_ + j1];
    const float bin0 = b_ih[2 * H_ + j0], bin1 = b_ih[2 * H_ + j1];
    const float bhr0 = b_hh[j0],          bhr1 = b_hh[j1];
    const float bhz0 = b_hh[H_ + j0],     bhz1 = b_hh[H_ + j1];
    const float bhn0 = b_hh[2 * H_ + j0], bhn1 = b_hh[2 * H_ + j1];

    float hj0 = 0.0f, hj1 = 0.0f;  // h state: MEANINGFUL IN LANE 63 ONLY
    uint32_t ver  = 1;    // ver 1 == initial zero state, lives in slot 1
    uint32_t dead = 0;    // leader watchdog state (wave-uniform)

    if (lane == 0)
        __hip_atomic_store(&h_buf[(ver & 1) * 256 + q], (uint64_t)ver << 32,
                           __ATOMIC_RELAXED, __HIP_MEMORY_SCOPE_AGENT);

    float xv[16];
    float iv = 0.0f;

    for (int b = 0; b < B_; ++b) {
        const int L = lens[b];
        if (L > 0) {
            iv = intervals[b * T_];
            const float* vrow = visit_emb + (size_t)(b * T_) * V_;
            #pragma unroll
            for (int u = 0; u < 16; ++u) xv[u] = vrow[lane + 64 * u];
        }
        for (int t = 0; t < L; ++t) {
            // ---- leader: ISSUE first sweep before x-dots ----------------
            const uint64_t* src = h_buf + (ver & 1) * 256;
            uint64_t w[4];
            if (wave == 0) {
                #pragma unroll
                for (int u = 0; u < 4; ++u)
                    w[u] = __hip_atomic_load(&src[lane + 64 * u],
                                             __ATOMIC_RELAXED,
                                             __HIP_MEMORY_SCOPE_AGENT);
            }

            // ---- x-side dots (h-independent; overlap the sweep) ---------
            const float xt = fmaf(iv, wt, bt);
            float ar0 = ir0[16] * xt, ar1 = ir1[16] * xt;
            float az0 = iz0[16] * xt, az1 = iz1[16] * xt;
            float xn0 = in0[16] * xt, xn1 = in1[16] * xt;
            #pragma unroll
            for (int u = 0; u < 16; ++u) {
                ar0 = fmaf(ir0[u], xv[u], ar0);
                ar1 = fmaf(ir1[u], xv[u], ar1);
                az0 = fmaf(iz0[u], xv[u], az0);
                az1 = fmaf(iz1[u], xv[u], az1);
                xn0 = fmaf(in0[u], xv[u], xn0);
                xn1 = fmaf(in1[u], xv[u], xn1);
            }
            // ---- prefetch next step's x row (in flight across barrier) --
            if (t + 1 < L) {
                iv = intervals[b * T_ + t + 1];
                const float* vrow = visit_emb + (size_t)(b * T_ + t + 1) * V_;
                #pragma unroll
                for (int u = 0; u < 16; ++u) xv[u] = vrow[lane + 64 * u];
            }

            // ---- leader: check tags (waitcnt lands here), retry, LDS ----
            if (wave == 0) {
                if (!dead) {
                    bool ok = true;
                    #pragma unroll
                    for (int u = 0; u < 4; ++u)
                        ok = ok && ((uint32_t)(w[u] >> 32) == ver);
                    uint32_t tries = 0;
                    while (!__all(ok)) {
                        if (++tries > (1u << 21)) { dead = 1; break; }
                        ok = true;
                        #pragma unroll
                        for (int u = 0; u < 4; ++u) {
                            w[u] = __hip_atomic_load(&src[lane + 64 * u],
                                                     __ATOMIC_RELAXED,
                                                     __HIP_MEMORY_SCOPE_AGENT);
                            ok = ok && ((uint32_t)(w[u] >> 32) == ver);
                        }
                    }
                }
                #pragma unroll
                for (int u = 0; u < 4; ++u) {
                    const uint32_t d = (uint32_t)w[u];
                    hs2[lane + 64 * u] =
                        make_float2(bf16_to_f32_(d & 0xFFFFu),
                                    bf16_to_f32_(d >> 16));
                }
            }
            __syncthreads();

            float h[8];
            #pragma unroll
            for (int u = 0; u < 8; ++u) h[u] = hs[lane + 64 * u];

            // ---- h-side dots; r/z merged with x-side, n kept split ------
            float hn0 = 0.0f, hn1 = 0.0f;
            #pragma unroll
            for (int u = 0; u < 8; ++u) {
                ar0 = fmaf(wr0[u], h[u], ar0);
                ar1 = fmaf(wr1[u], h[u], ar1);
                az0 = fmaf(wz0[u], h[u], az0);
                az1 = fmaf(wz1[u], h[u], az1);
                hn0 = fmaf(wn0[u], h[u], hn0);
                hn1 = fmaf(wn1[u], h[u], hn1);
            }

            // ---- 8 pipelined DPP sums -> results land in lane 63 --------
            const float sr0 = wave_sum63_(ar0), sr1 = wave_sum63_(ar1);
            const float sz0 = wave_sum63_(az0), sz1 = wave_sum63_(az1);
            const float sx0 = wave_sum63_(xn0), sx1 = wave_sum63_(xn1);
            const float sh0 = wave_sum63_(hn0), sh1 = wave_sum63_(hn1);

            // ---- gates & recurrence: SIMT-wide, meaningful in lane 63 ---
            const float r0 = sigmoidf_(sr0 + bir0 + bhr0);
            const float r1 = sigmoidf_(sr1 + bir1 + bhr1);
            const float z0 = sigmoidf_(sz0 + biz0 + bhz0);
            const float z1 = sigmoidf_(sz1 + biz1 + bhz1);
            const float n0 = tanhf_(sx0 + bin0 + r0 * (sh0 + bhn0));
            const float n1 = tanhf_(sx1 + bin1 + r1 * (sh1 + bhn1));
            hj0 = (1.0f - z0) * n0 + z0 * hj0;
            hj1 = (1.0f - z1) * n1 + z1 * hj1;

            // ---- publish ONE tagged packed word, direct from lane 63 ----
            ++ver;
            if (lane == 63) {
                const uint32_t packed =
                    bf16_rn_(hj0) | (bf16_rn_(hj1) << 16);
                __hip_atomic_store(&h_buf[(ver & 1) * 256 + q],
                    ((uint64_t)ver << 32) | (uint64_t)packed,
                    __ATOMIC_RELAXED, __HIP_MEMORY_SCOPE_AGENT);
            }
        }
        // out[b] = h after sample b's (possibly empty) segment
        // (lane 63 holds the authoritative state; 128x total, off hot path)
        if (lane == 63) {
            out[b * H_ + j0] = hj0;
            out[b * H_ + j1] = hj1;
        }
    }

    // last wave signals the heaters to stop (everyone else is within +-1
    // step of q==255, so heat never extends the dispatch)
    if (q == 255 && lane == 63)
        __hip_atomic_store(done_w, 1u, __ATOMIC_RELAXED,
                           __HIP_MEMORY_SCOPE_AGENT);
}

// ---------------------------------------------------------------------------
extern "C" void kernel_launch(void* const* d_in, const int* in_sizes, int n_in,
                              void* d_out, int out_size, void* d_ws, size_t ws_size,
                              hipStream_t stream)
{
    const float* visit_emb = (const float*)d_in[0];
    const float* intervals = (const float*)d_in[1];
    const float* W_time    = (const float*)d_in[2];
    const float* b_time    = (const float*)d_in[3];
    const float* W_ih      = (const float*)d_in[4];
    const float* W_hh      = (const float*)d_in[5];
    const float* b_ih      = (const float*)d_in[6];
    const float* b_hh      = (const float*)d_in[7];
    const int*   lens      = (const int*)d_in[8];
    float*       out       = (float*)d_out;

    // workspace: [0,4KB) packed tagged h exchange; [4KB) done; [4224) sink
    uint64_t* h_buf = (uint64_t*)d_ws;

    gru_fused<<<256, 256, 0, stream>>>(visit_emb, intervals, W_time, b_time,
                                       W_ih, W_hh, b_ih, b_hh, lens, h_buf, out);
}

// Round 9
// 6697.028 us; speedup vs baseline: 1.7131x; 1.0361x over previous
//
#include <hip/hip_runtime.h>
#include <stdint.h>

#define B_   128
#define T_   64
#define V_   1024
#define TS_  64
#define H_   512
#define K_   (V_ + TS_)   // 1088

// ---------------------------------------------------------------------------
// Fused time-aware GRU scan, round 21 = r20 (6.94ms best) + fast-gate serial
// cuts (the serial-cut family is 2-for-2; all other families 0-for-7).
//
// Changes vs r20 (all VALU-local, zero protocol/traffic delta):
//  1. Six full-precision divisions per step (4 sigmoid + 2 tanh) replaced
//     with raw v_rcp_f32 (inline asm). Default hipcc division is the
//     v_div_scale/v_rcp/v_div_fmas/v_div_fixup sequence (~15-20cy serial
//     each ~= 100cy/step of divide machinery). rcp error ~1ulp, negligible
//     vs the protocol's bf16 h-quantization (2^-8).
//     tanh = 1 - 2/(e^{2x}+1); sigmoid = 1/(1+e^{-x}) via rcp.
//  2. Publish pack: manual round+shift+or (~10 VALU) -> one
//     v_cvt_pk_bf16_f32 (RNE; hj0 low half, hj1 high half, same layout).
//  3. Chain reorder: sums ordered sr/sh first, z last; n-chain starts as
//     soon as sr/sh land; hj = fmaf(z, hj-n, n).
//
// Ledger (do-not-revisit):
//   - issue-ahead/pipelined polling REFUTED (r13/r15 8.7ms, r16 10.2ms).
//   - LDS x-staging REFUTED (r17 11.5ms): ds_write vmcnt drain + barrier
//     lgkmcnt drain put the x-row load INSIDE the step's barrier window.
//   - heater poll-rate cut NEUTRAL (r19): background traffic not limiting.
//   - traffic knobs dead at 64 pollers (r7/r8/r9); 256 pollers catastrophic.
//   - serial cuts WORK: r10 +16%, r20 lane-63 publish -4.5%.
// Model: step ~1.7us = cross-XCD publish visibility + poll resolve +
// straggler max-of-256 + compute tail. This round shaves the compute tail
// (~100-150cy of ~4300cy).
//
// Worker structure: 64 WGs x 4 waves; wave q owns h[2q],h[2q+1]; leader
// polls the packed tagged exchange (ver<<32)|(bf16(hj1)<<16)|bf16(hj0),
// 4 loads/lane over 256 words, issued BEFORE x-dots, LDS broadcast +
// 1 barrier; DPP reduction to lane 63; gates SIMT-wide (lane 63
// meaningful); publish direct from lane 63.
// Workspace: [0,4KB) h_buf, [4KB,+64B) done word, [4224,...) heater sink.
// ---------------------------------------------------------------------------

__device__ __forceinline__ float rcp_(float x) {
    float r;
    asm("v_rcp_f32 %0, %1" : "=v"(r) : "v"(x));
    return r;
}
__device__ __forceinline__ float sigmoidf_(float x) {
    return rcp_(1.0f + __expf(-x));          // ~1ulp rcp, fine vs bf16 h
}
__device__ __forceinline__ float tanhf_(float x) {
    x = fminf(fmaxf(x, -15.0f), 15.0f);
    const float e = __expf(2.0f * x);
    return fmaf(-2.0f, rcp_(e + 1.0f), 1.0f); // (e-1)/(e+1) == 1-2/(e+1)
}
__device__ __forceinline__ float bf16_to_f32_(uint32_t b) {
    return __uint_as_float(b << 16);
}

// GCN DPP partial-wave sum: after this chain the FULL 64-lane sum is valid
// in lane 63 (r10-verified chain, minus the readlane broadcast).
template <int CTRL, int RM, int BM>
__device__ __forceinline__ float dpp_add_(float a) {
    const int x = __builtin_amdgcn_update_dpp(
        0, __float_as_int(a), CTRL, RM, BM, true);
    return a + __int_as_float(x);
}
__device__ __forceinline__ float wave_sum63_(float a) {
    a = dpp_add_<0x111, 0xF, 0xF>(a);
    a = dpp_add_<0x112, 0xF, 0xF>(a);
    a = dpp_add_<0x114, 0xF, 0xE>(a);
    a = dpp_add_<0x118, 0xF, 0xC>(a);
    a = dpp_add_<0x142, 0xA, 0xF>(a);
    a = dpp_add_<0x143, 0xC, 0xF>(a);
    return a;                          // valid in lane 63 only
}

__global__ __launch_bounds__(256, 1) void gru_fused(
    const float* __restrict__ visit_emb, const float* __restrict__ intervals,
    const float* __restrict__ W_time, const float* __restrict__ b_time,
    const float* __restrict__ W_ih, const float* __restrict__ W_hh,
    const float* __restrict__ b_ih, const float* __restrict__ b_hh,
    const int* __restrict__ lens,
    uint64_t* h_buf /* [2 slot][256] tagged packed */,
    float* __restrict__ out)
{
    uint32_t* done_w = (uint32_t*)((char*)h_buf + 4096);

    // =================== HEATER BLOCKS (blockIdx >= 64) ==================
    if (blockIdx.x >= 64) {
        float a0 = (float)(blockIdx.x * 256 + threadIdx.x) * 1e-6f + 1.01f;
        float a1 = a0 + 0.1f, a2 = a0 + 0.2f, a3 = a0 + 0.3f;
        const float c = 1.0000001f, d = 1e-7f;
        // poll done_w every ~1024 FMAs; bounded spin ~28ms at 2.4GHz
        for (uint32_t it = 0; it < (1u << 15); ++it) {
            #pragma unroll
            for (int o = 0; o < 4; ++o) {
                #pragma unroll
                for (int i = 0; i < 64; ++i) { // 4 indep chains -> full issue
                    a0 = fmaf(a0, c, d);
                    a1 = fmaf(a1, c, d);
                    a2 = fmaf(a2, c, d);
                    a3 = fmaf(a3, c, d);
                }
            }
            const uint32_t f = __hip_atomic_load(done_w, __ATOMIC_RELAXED,
                                                 __HIP_MEMORY_SCOPE_AGENT);
            if (f == 1u) break;
        }
        const float s = a0 + a1 + a2 + a3;
        if (s == 1234.56789f && threadIdx.x == 0)   // defeat DCE; never true
            ((float*)((char*)h_buf + 4224))[blockIdx.x] = s;
        return;
    }

    // =================== WORKER BLOCKS ===================================
    const int lane = threadIdx.x & 63;
    const int wave = threadIdx.x >> 6;        // 0..3
    const int q    = blockIdx.x * 4 + wave;   // 0..255 global wave id
    const int j0   = q * 2;
    const int j1   = j0 + 1;

    __shared__ float2 hs2[256];               // unpacked h pairs (fp32)
    float* hs = (float*)hs2;                  // alias: hs[512]

    float wr0[8], wr1[8], wz0[8], wz1[8], wn0[8], wn1[8];
    #pragma unroll
    for (int u = 0; u < 8; ++u) {
        const int k = lane + 64 * u;
        wr0[u] = W_hh[(size_t)j0 * H_ + k];
        wr1[u] = W_hh[(size_t)j1 * H_ + k];
        wz0[u] = W_hh[(size_t)(H_ + j0) * H_ + k];
        wz1[u] = W_hh[(size_t)(H_ + j1) * H_ + k];
        wn0[u] = W_hh[(size_t)(2 * H_ + j0) * H_ + k];
        wn1[u] = W_hh[(size_t)(2 * H_ + j1) * H_ + k];
    }
    float ir0[17], ir1[17], iz0[17], iz1[17], in0[17], in1[17];
    #pragma unroll
    for (int u = 0; u < 16; ++u) {
        const int k = lane + 64 * u;
        ir0[u] = W_ih[(size_t)j0 * K_ + k];
        ir1[u] = W_ih[(size_t)j1 * K_ + k];
        iz0[u] = W_ih[(size_t)(H_ + j0) * K_ + k];
        iz1[u] = W_ih[(size_t)(H_ + j1) * K_ + k];
        in0[u] = W_ih[(size_t)(2 * H_ + j0) * K_ + k];
        in1[u] = W_ih[(size_t)(2 * H_ + j1) * K_ + k];
    }
    ir0[16] = W_ih[(size_t)j0 * K_ + V_ + lane];
    ir1[16] = W_ih[(size_t)j1 * K_ + V_ + lane];
    iz0[16] = W_ih[(size_t)(H_ + j0) * K_ + V_ + lane];
    iz1[16] = W_ih[(size_t)(H_ + j1) * K_ + V_ + lane];
    in0[16] = W_ih[(size_t)(2 * H_ + j0) * K_ + V_ + lane];
    in1[16] = W_ih[(size_t)(2 * H_ + j1) * K_ + V_ + lane];

    const float wt = W_time[lane];
    const float bt = b_time[lane];

    const float bir0 = b_ih[j0],          bir1 = b_ih[j1];
    const float biz0 = b_ih[H_ + j0],     biz1 = b_ih[H_ + j1];
    const float bin0 = b_ih[2 * H_ + j0], bin1 = b_ih[2 * H_ + j1];
    const float bhr0 = b_hh[j0],          bhr1 = b_hh[j1];
    const float bhz0 = b_hh[H_ + j0],     bhz1 = b_hh[H_ + j1];
    const float bhn0 = b_hh[2 * H_ + j0], bhn1 = b_hh[2 * H_ + j1];

    float hj0 = 0.0f, hj1 = 0.0f;  // h state: MEANINGFUL IN LANE 63 ONLY
    uint32_t ver  = 1;    // ver 1 == initial zero state, lives in slot 1
    uint32_t dead = 0;    // leader watchdog state (wave-uniform)

    if (lane == 0)
        __hip_atomic_store(&h_buf[(ver & 1) * 256 + q], (uint64_t)ver << 32,
                           __ATOMIC_RELAXED, __HIP_MEMORY_SCOPE_AGENT);

    float xv[16];
    float iv = 0.0f;

    for (int b = 0; b < B_; ++b) {
        const int L = lens[b];
        if (L > 0) {
            iv = intervals[b * T_];
            const float* vrow = visit_emb + (size_t)(b * T_) * V_;
            #pragma unroll
            for (int u = 0; u < 16; ++u) xv[u] = vrow[lane + 64 * u];
        }
        for (int t = 0; t < L; ++t) {
            // ---- leader: ISSUE first sweep before x-dots ----------------
            const uint64_t* src = h_buf + (ver & 1) * 256;
            uint64_t w[4];
            if (wave == 0) {
                #pragma unroll
                for (int u = 0; u < 4; ++u)
                    w[u] = __hip_atomic_load(&src[lane + 64 * u],
                                             __ATOMIC_RELAXED,
                                             __HIP_MEMORY_SCOPE_AGENT);
            }

            // ---- x-side dots (h-independent; overlap the sweep) ---------
            const float xt = fmaf(iv, wt, bt);
            float ar0 = ir0[16] * xt, ar1 = ir1[16] * xt;
            float az0 = iz0[16] * xt, az1 = iz1[16] * xt;
            float xn0 = in0[16] * xt, xn1 = in1[16] * xt;
            #pragma unroll
            for (int u = 0; u < 16; ++u) {
                ar0 = fmaf(ir0[u], xv[u], ar0);
                ar1 = fmaf(ir1[u], xv[u], ar1);
                az0 = fmaf(iz0[u], xv[u], az0);
                az1 = fmaf(iz1[u], xv[u], az1);
                xn0 = fmaf(in0[u], xv[u], xn0);
                xn1 = fmaf(in1[u], xv[u], xn1);
            }
            // ---- prefetch next step's x row (in flight across barrier) --
            if (t + 1 < L) {
                iv = intervals[b * T_ + t + 1];
                const float* vrow = visit_emb + (size_t)(b * T_ + t + 1) * V_;
                #pragma unroll
                for (int u = 0; u < 16; ++u) xv[u] = vrow[lane + 64 * u];
            }

            // ---- leader: check tags (waitcnt lands here), retry, LDS ----
            if (wave == 0) {
                if (!dead) {
                    bool ok = true;
                    #pragma unroll
                    for (int u = 0; u < 4; ++u)
                        ok = ok && ((uint32_t)(w[u] >> 32) == ver);
                    uint32_t tries = 0;
                    while (!__all(ok)) {
                        if (++tries > (1u << 21)) { dead = 1; break; }
                        ok = true;
                        #pragma unroll
                        for (int u = 0; u < 4; ++u) {
                            w[u] = __hip_atomic_load(&src[lane + 64 * u],
                                                     __ATOMIC_RELAXED,
                                                     __HIP_MEMORY_SCOPE_AGENT);
                            ok = ok && ((uint32_t)(w[u] >> 32) == ver);
                        }
                    }
                }
                #pragma unroll
                for (int u = 0; u < 4; ++u) {
                    const uint32_t d = (uint32_t)w[u];
                    hs2[lane + 64 * u] =
                        make_float2(bf16_to_f32_(d & 0xFFFFu),
                                    bf16_to_f32_(d >> 16));
                }
            }
            __syncthreads();

            float h[8];
            #pragma unroll
            for (int u = 0; u < 8; ++u) h[u] = hs[lane + 64 * u];

            // ---- h-side dots; r/z merged with x-side, n kept split ------
            float hn0 = 0.0f, hn1 = 0.0f;
            #pragma unroll
            for (int u = 0; u < 8; ++u) {
                ar0 = fmaf(wr0[u], h[u], ar0);
                ar1 = fmaf(wr1[u], h[u], ar1);
                az0 = fmaf(wz0[u], h[u], az0);
                az1 = fmaf(wz1[u], h[u], az1);
                hn0 = fmaf(wn0[u], h[u], hn0);
                hn1 = fmaf(wn1[u], h[u], hn1);
            }

            // ---- 8 pipelined DPP sums -> lane 63; r/h first, z last -----
            const float sr0 = wave_sum63_(ar0), sr1 = wave_sum63_(ar1);
            const float sh0 = wave_sum63_(hn0), sh1 = wave_sum63_(hn1);
            const float sx0 = wave_sum63_(xn0), sx1 = wave_sum63_(xn1);
            const float sz0 = wave_sum63_(az0), sz1 = wave_sum63_(az1);

            // ---- gates & recurrence (SIMT-wide, lane 63 meaningful) -----
            // critical chain: sr->r->fma->tanh->hj fma; z parallel.
            const float r0 = sigmoidf_(sr0 + bir0 + bhr0);
            const float r1 = sigmoidf_(sr1 + bir1 + bhr1);
            const float n0 = tanhf_(sx0 + bin0 + r0 * (sh0 + bhn0));
            const float n1 = tanhf_(sx1 + bin1 + r1 * (sh1 + bhn1));
            const float z0 = sigmoidf_(sz0 + biz0 + bhz0);
            const float z1 = sigmoidf_(sz1 + biz1 + bhz1);
            hj0 = fmaf(z0, hj0 - n0, n0);
            hj1 = fmaf(z1, hj1 - n1, n1);

            // ---- publish ONE tagged packed word, direct from lane 63 ----
            ++ver;
            if (lane == 63) {
                uint32_t packed;   // lo = bf16(hj0), hi = bf16(hj1), RNE
                asm("v_cvt_pk_bf16_f32 %0, %1, %2"
                    : "=v"(packed) : "v"(hj0), "v"(hj1));
                __hip_atomic_store(&h_buf[(ver & 1) * 256 + q],
                    ((uint64_t)ver << 32) | (uint64_t)packed,
                    __ATOMIC_RELAXED, __HIP_MEMORY_SCOPE_AGENT);
            }
        }
        // out[b] = h after sample b's (possibly empty) segment
        // (lane 63 holds the authoritative state; 128x total, off hot path)
        if (lane == 63) {
            out[b * H_ + j0] = hj0;
            out[b * H_ + j1] = hj1;
        }
    }

    // last wave signals the heaters to stop (everyone else is within +-1
    // step of q==255, so heat never extends the dispatch)
    if (q == 255 && lane == 63)
        __hip_atomic_store(done_w, 1u, __ATOMIC_RELAXED,
                           __HIP_MEMORY_SCOPE_AGENT);
}

// ---------------------------------------------------------------------------
extern "C" void kernel_launch(void* const* d_in, const int* in_sizes, int n_in,
                              void* d_out, int out_size, void* d_ws, size_t ws_size,
                              hipStream_t stream)
{
    const float* visit_emb = (const float*)d_in[0];
    const float* intervals = (const float*)d_in[1];
    const float* W_time    = (const float*)d_in[2];
    const float* b_time    = (const float*)d_in[3];
    const float* W_ih      = (const float*)d_in[4];
    const float* W_hh      = (const float*)d_in[5];
    const float* b_ih      = (const float*)d_in[6];
    const float* b_hh      = (const float*)d_in[7];
    const int*   lens      = (const int*)d_in[8];
    float*       out       = (float*)d_out;

    // workspace: [0,4KB) packed tagged h exchange; [4KB) done; [4224) sink
    uint64_t* h_buf = (uint64_t*)d_ws;

    gru_fused<<<256, 256, 0, stream>>>(visit_emb, intervals, W_time, b_time,
                                       W_ih, W_hh, b_ih, b_hh, lens, h_buf, out);
}

// Round 10
// 6635.508 us; speedup vs baseline: 1.7290x; 1.0093x over previous
//
#include <hip/hip_runtime.h>
#include <stdint.h>

#define B_   128
#define T_   64
#define V_   1024
#define TS_  64
#define H_   512
#define K_   (V_ + TS_)   // 1088

// ---------------------------------------------------------------------------
// Fused time-aware GRU scan, round 22 = r21 (6.70ms best) + leader-deferred
// post-barrier x-prefetch (serial-cut family, 3-for-3; all others 0-for-7).
//
// Change vs r21 (zero traffic/protocol delta): ONLY the leader wave's 17-load
// x-row prefetch moves from pre-retry to AFTER __syncthreads. Why it's safe
// and a cut:
//  - waves 1..3 prefetch the IDENTICAL row pre-barrier (same addresses) ->
//    leader's deferred loads are L1 hits (~30-100cy) with ~400cy of cover
//    (h-dots/sums/gates/publish) before next step's x-dots consume them.
//  - leader's vmcnt queue during the retry loop now contains POLLS ONLY:
//    in-order vmcnt retirement means the first retry consumption previously
//    drained the outstanding prefetch too (and the pre-barrier vmcnt(0)
//    drain included it). Both exposures removed from the serial chain.
//  - this is r13's "BUG2" lever re-tested WITHOUT the issue-ahead-poll
//    traffic that poisoned r13/r16, and WITHOUT r17's ds_write trap.
//
// Ledger (do-not-revisit):
//   - issue-ahead/pipelined polling REFUTED (r13/r15 8.7ms, r16 10.2ms).
//   - LDS x-staging REFUTED (r17 11.5ms): ds_write vmcnt drain + barrier
//     lgkmcnt drain put the x-row load INSIDE the step's barrier window.
//   - heater poll-rate cut NEUTRAL (r19): background traffic not limiting.
//   - traffic knobs dead at 64 pollers (r7/r8/r9); 256 pollers catastrophic.
//   - serial cuts WORK: r10 +16%, r20 lane-63 publish -4.5%, r21 fast gates
//     -3.5%.
// Model: step ~1.66us ~= 4000cy = publish visibility + poll resolve (+
// retries) + straggler skew + ~400cy compute tail. This round removes the
// prefetch-drain exposure (~100-400cy on retry steps).
//
// Worker structure: 64 WGs x 4 waves; wave q owns h[2q],h[2q+1]; leader
// polls the packed tagged exchange (ver<<32)|(bf16(hj1)<<16)|bf16(hj0),
// 4 loads/lane over 256 words, issued BEFORE x-dots, LDS broadcast +
// 1 barrier; DPP reduction to lane 63; gates SIMT-wide (lane 63
// meaningful); publish direct from lane 63 via v_cvt_pk_bf16_f32.
// Workspace: [0,4KB) h_buf, [4KB,+64B) done word, [4224,...) heater sink.
// ---------------------------------------------------------------------------

__device__ __forceinline__ float rcp_(float x) {
    float r;
    asm("v_rcp_f32 %0, %1" : "=v"(r) : "v"(x));
    return r;
}
__device__ __forceinline__ float sigmoidf_(float x) {
    return rcp_(1.0f + __expf(-x));          // ~1ulp rcp, fine vs bf16 h
}
__device__ __forceinline__ float tanhf_(float x) {
    x = fminf(fmaxf(x, -15.0f), 15.0f);
    const float e = __expf(2.0f * x);
    return fmaf(-2.0f, rcp_(e + 1.0f), 1.0f); // (e-1)/(e+1) == 1-2/(e+1)
}
__device__ __forceinline__ float bf16_to_f32_(uint32_t b) {
    return __uint_as_float(b << 16);
}

// GCN DPP partial-wave sum: after this chain the FULL 64-lane sum is valid
// in lane 63 (r10-verified chain, minus the readlane broadcast).
template <int CTRL, int RM, int BM>
__device__ __forceinline__ float dpp_add_(float a) {
    const int x = __builtin_amdgcn_update_dpp(
        0, __float_as_int(a), CTRL, RM, BM, true);
    return a + __int_as_float(x);
}
__device__ __forceinline__ float wave_sum63_(float a) {
    a = dpp_add_<0x111, 0xF, 0xF>(a);
    a = dpp_add_<0x112, 0xF, 0xF>(a);
    a = dpp_add_<0x114, 0xF, 0xE>(a);
    a = dpp_add_<0x118, 0xF, 0xC>(a);
    a = dpp_add_<0x142, 0xA, 0xF>(a);
    a = dpp_add_<0x143, 0xC, 0xF>(a);
    return a;                          // valid in lane 63 only
}

__global__ __launch_bounds__(256, 1) void gru_fused(
    const float* __restrict__ visit_emb, const float* __restrict__ intervals,
    const float* __restrict__ W_time, const float* __restrict__ b_time,
    const float* __restrict__ W_ih, const float* __restrict__ W_hh,
    const float* __restrict__ b_ih, const float* __restrict__ b_hh,
    const int* __restrict__ lens,
    uint64_t* h_buf /* [2 slot][256] tagged packed */,
    float* __restrict__ out)
{
    uint32_t* done_w = (uint32_t*)((char*)h_buf + 4096);

    // =================== HEATER BLOCKS (blockIdx >= 64) ==================
    if (blockIdx.x >= 64) {
        float a0 = (float)(blockIdx.x * 256 + threadIdx.x) * 1e-6f + 1.01f;
        float a1 = a0 + 0.1f, a2 = a0 + 0.2f, a3 = a0 + 0.3f;
        const float c = 1.0000001f, d = 1e-7f;
        // poll done_w every ~1024 FMAs; bounded spin ~28ms at 2.4GHz
        for (uint32_t it = 0; it < (1u << 15); ++it) {
            #pragma unroll
            for (int o = 0; o < 4; ++o) {
                #pragma unroll
                for (int i = 0; i < 64; ++i) { // 4 indep chains -> full issue
                    a0 = fmaf(a0, c, d);
                    a1 = fmaf(a1, c, d);
                    a2 = fmaf(a2, c, d);
                    a3 = fmaf(a3, c, d);
                }
            }
            const uint32_t f = __hip_atomic_load(done_w, __ATOMIC_RELAXED,
                                                 __HIP_MEMORY_SCOPE_AGENT);
            if (f == 1u) break;
        }
        const float s = a0 + a1 + a2 + a3;
        if (s == 1234.56789f && threadIdx.x == 0)   // defeat DCE; never true
            ((float*)((char*)h_buf + 4224))[blockIdx.x] = s;
        return;
    }

    // =================== WORKER BLOCKS ===================================
    const int lane = threadIdx.x & 63;
    const int wave = threadIdx.x >> 6;        // 0..3
    const int q    = blockIdx.x * 4 + wave;   // 0..255 global wave id
    const int j0   = q * 2;
    const int j1   = j0 + 1;

    __shared__ float2 hs2[256];               // unpacked h pairs (fp32)
    float* hs = (float*)hs2;                  // alias: hs[512]

    float wr0[8], wr1[8], wz0[8], wz1[8], wn0[8], wn1[8];
    #pragma unroll
    for (int u = 0; u < 8; ++u) {
        const int k = lane + 64 * u;
        wr0[u] = W_hh[(size_t)j0 * H_ + k];
        wr1[u] = W_hh[(size_t)j1 * H_ + k];
        wz0[u] = W_hh[(size_t)(H_ + j0) * H_ + k];
        wz1[u] = W_hh[(size_t)(H_ + j1) * H_ + k];
        wn0[u] = W_hh[(size_t)(2 * H_ + j0) * H_ + k];
        wn1[u] = W_hh[(size_t)(2 * H_ + j1) * H_ + k];
    }
    float ir0[17], ir1[17], iz0[17], iz1[17], in0[17], in1[17];
    #pragma unroll
    for (int u = 0; u < 16; ++u) {
        const int k = lane + 64 * u;
        ir0[u] = W_ih[(size_t)j0 * K_ + k];
        ir1[u] = W_ih[(size_t)j1 * K_ + k];
        iz0[u] = W_ih[(size_t)(H_ + j0) * K_ + k];
        iz1[u] = W_ih[(size_t)(H_ + j1) * K_ + k];
        in0[u] = W_ih[(size_t)(2 * H_ + j0) * K_ + k];
        in1[u] = W_ih[(size_t)(2 * H_ + j1) * K_ + k];
    }
    ir0[16] = W_ih[(size_t)j0 * K_ + V_ + lane];
    ir1[16] = W_ih[(size_t)j1 * K_ + V_ + lane];
    iz0[16] = W_ih[(size_t)(H_ + j0) * K_ + V_ + lane];
    iz1[16] = W_ih[(size_t)(H_ + j1) * K_ + V_ + lane];
    in0[16] = W_ih[(size_t)(2 * H_ + j0) * K_ + V_ + lane];
    in1[16] = W_ih[(size_t)(2 * H_ + j1) * K_ + V_ + lane];

    const float wt = W_time[lane];
    const float bt = b_time[lane];

    const float bir0 = b_ih[j0],          bir1 = b_ih[j1];
    const float biz0 = b_ih[H_ + j0],     biz1 = b_ih[H_ + j1];
    const float bin0 = b_ih[2 * H_ + j0], bin1 = b_ih[2 * H_ + j1];
    const float bhr0 = b_hh[j0],          bhr1 = b_hh[j1];
    const float bhz0 = b_hh[H_ + j0],     bhz1 = b_hh[H_ + j1];
    const float bhn0 = b_hh[2 * H_ + j0], bhn1 = b_hh[2 * H_ + j1];

    float hj0 = 0.0f, hj1 = 0.0f;  // h state: MEANINGFUL IN LANE 63 ONLY
    uint32_t ver  = 1;    // ver 1 == initial zero state, lives in slot 1
    uint32_t dead = 0;    // leader watchdog state (wave-uniform)

    if (lane == 0)
        __hip_atomic_store(&h_buf[(ver & 1) * 256 + q], (uint64_t)ver << 32,
                           __ATOMIC_RELAXED, __HIP_MEMORY_SCOPE_AGENT);

    float xv[16];
    float iv = 0.0f;

    for (int b = 0; b < B_; ++b) {
        const int L = lens[b];
        if (L > 0) {
            iv = intervals[b * T_];
            const float* vrow = visit_emb + (size_t)(b * T_) * V_;
            #pragma unroll
            for (int u = 0; u < 16; ++u) xv[u] = vrow[lane + 64 * u];
        }
        for (int t = 0; t < L; ++t) {
            // ---- leader: ISSUE first sweep before x-dots ----------------
            const uint64_t* src = h_buf + (ver & 1) * 256;
            uint64_t w[4];
            if (wave == 0) {
                #pragma unroll
                for (int u = 0; u < 4; ++u)
                    w[u] = __hip_atomic_load(&src[lane + 64 * u],
                                             __ATOMIC_RELAXED,
                                             __HIP_MEMORY_SCOPE_AGENT);
            }

            // ---- x-side dots (h-independent; overlap the sweep) ---------
            const float xt = fmaf(iv, wt, bt);
            float ar0 = ir0[16] * xt, ar1 = ir1[16] * xt;
            float az0 = iz0[16] * xt, az1 = iz1[16] * xt;
            float xn0 = in0[16] * xt, xn1 = in1[16] * xt;
            #pragma unroll
            for (int u = 0; u < 16; ++u) {
                ar0 = fmaf(ir0[u], xv[u], ar0);
                ar1 = fmaf(ir1[u], xv[u], ar1);
                az0 = fmaf(iz0[u], xv[u], az0);
                az1 = fmaf(iz1[u], xv[u], az1);
                xn0 = fmaf(in0[u], xv[u], xn0);
                xn1 = fmaf(in1[u], xv[u], xn1);
            }
            // ---- non-leaders: prefetch next x row (drains at barrier
            //      while the leader polls; leader's copy comes later) -----
            if (wave != 0 && t + 1 < L) {
                iv = intervals[b * T_ + t + 1];
                const float* vrow = visit_emb + (size_t)(b * T_ + t + 1) * V_;
                #pragma unroll
                for (int u = 0; u < 16; ++u) xv[u] = vrow[lane + 64 * u];
            }

            // ---- leader: check tags (queue = polls only), retry, LDS ----
            if (wave == 0) {
                if (!dead) {
                    bool ok = true;
                    #pragma unroll
                    for (int u = 0; u < 4; ++u)
                        ok = ok && ((uint32_t)(w[u] >> 32) == ver);
                    uint32_t tries = 0;
                    while (!__all(ok)) {
                        if (++tries > (1u << 21)) { dead = 1; break; }
                        ok = true;
                        #pragma unroll
                        for (int u = 0; u < 4; ++u) {
                            w[u] = __hip_atomic_load(&src[lane + 64 * u],
                                                     __ATOMIC_RELAXED,
                                                     __HIP_MEMORY_SCOPE_AGENT);
                            ok = ok && ((uint32_t)(w[u] >> 32) == ver);
                        }
                    }
                }
                #pragma unroll
                for (int u = 0; u < 4; ++u) {
                    const uint32_t d = (uint32_t)w[u];
                    hs2[lane + 64 * u] =
                        make_float2(bf16_to_f32_(d & 0xFFFFu),
                                    bf16_to_f32_(d >> 16));
                }
            }
            __syncthreads();

            // ---- leader: deferred prefetch (L1-warm: waves 1..3 loaded
            //      the same row pre-barrier). ~400cy of cover before next
            //      step's x-dots; retry queue stays poll-only. ------------
            if (wave == 0 && t + 1 < L) {
                iv = intervals[b * T_ + t + 1];
                const float* vrow = visit_emb + (size_t)(b * T_ + t + 1) * V_;
                #pragma unroll
                for (int u = 0; u < 16; ++u) xv[u] = vrow[lane + 64 * u];
            }

            float h[8];
            #pragma unroll
            for (int u = 0; u < 8; ++u) h[u] = hs[lane + 64 * u];

            // ---- h-side dots; r/z merged with x-side, n kept split ------
            float hn0 = 0.0f, hn1 = 0.0f;
            #pragma unroll
            for (int u = 0; u < 8; ++u) {
                ar0 = fmaf(wr0[u], h[u], ar0);
                ar1 = fmaf(wr1[u], h[u], ar1);
                az0 = fmaf(wz0[u], h[u], az0);
                az1 = fmaf(wz1[u], h[u], az1);
                hn0 = fmaf(wn0[u], h[u], hn0);
                hn1 = fmaf(wn1[u], h[u], hn1);
            }

            // ---- 8 pipelined DPP sums -> lane 63; r/h first, z last -----
            const float sr0 = wave_sum63_(ar0), sr1 = wave_sum63_(ar1);
            const float sh0 = wave_sum63_(hn0), sh1 = wave_sum63_(hn1);
            const float sx0 = wave_sum63_(xn0), sx1 = wave_sum63_(xn1);
            const float sz0 = wave_sum63_(az0), sz1 = wave_sum63_(az1);

            // ---- gates & recurrence (SIMT-wide, lane 63 meaningful) -----
            // critical chain: sr->r->fma->tanh->hj fma; z parallel.
            const float r0 = sigmoidf_(sr0 + bir0 + bhr0);
            const float r1 = sigmoidf_(sr1 + bir1 + bhr1);
            const float n0 = tanhf_(sx0 + bin0 + r0 * (sh0 + bhn0));
            const float n1 = tanhf_(sx1 + bin1 + r1 * (sh1 + bhn1));
            const float z0 = sigmoidf_(sz0 + biz0 + bhz0);
            const float z1 = sigmoidf_(sz1 + biz1 + bhz1);
            hj0 = fmaf(z0, hj0 - n0, n0);
            hj1 = fmaf(z1, hj1 - n1, n1);

            // ---- publish ONE tagged packed word, direct from lane 63 ----
            ++ver;
            if (lane == 63) {
                uint32_t packed;   // lo = bf16(hj0), hi = bf16(hj1), RNE
                asm("v_cvt_pk_bf16_f32 %0, %1, %2"
                    : "=v"(packed) : "v"(hj0), "v"(hj1));
                __hip_atomic_store(&h_buf[(ver & 1) * 256 + q],
                    ((uint64_t)ver << 32) | (uint64_t)packed,
                    __ATOMIC_RELAXED, __HIP_MEMORY_SCOPE_AGENT);
            }
        }
        // out[b] = h after sample b's (possibly empty) segment
        // (lane 63 holds the authoritative state; 128x total, off hot path)
        if (lane == 63) {
            out[b * H_ + j0] = hj0;
            out[b * H_ + j1] = hj1;
        }
    }

    // last wave signals the heaters to stop (everyone else is within +-1
    // step of q==255, so heat never extends the dispatch)
    if (q == 255 && lane == 63)
        __hip_atomic_store(done_w, 1u, __ATOMIC_RELAXED,
                           __HIP_MEMORY_SCOPE_AGENT);
}

// ---------------------------------------------------------------------------
extern "C" void kernel_launch(void* const* d_in, const int* in_sizes, int n_in,
                              void* d_out, int out_size, void* d_ws, size_t ws_size,
                              hipStream_t stream)
{
    const float* visit_emb = (const float*)d_in[0];
    const float* intervals = (const float*)d_in[1];
    const float* W_time    = (const float*)d_in[2];
    const float* b_time    = (const float*)d_in[3];
    const float* W_ih      = (const float*)d_in[4];
    const float* W_hh      = (const float*)d_in[5];
    const float* b_ih      = (const float*)d_in[6];
    const float* b_hh      = (const float*)d_in[7];
    const int*   lens      = (const int*)d_in[8];
    float*       out       = (float*)d_out;

    // workspace: [0,4KB) packed tagged h exchange; [4KB) done; [4224) sink
    uint64_t* h_buf = (uint64_t*)d_ws;

    gru_fused<<<256, 256, 0, stream>>>(visit_emb, intervals, W_time, b_time,
                                       W_ih, W_hh, b_ih, b_hh, lens, h_buf, out);
}